// Round 6
// baseline (4946.464 us; speedup 1.0000x reference)
//
#include <hip/hip_runtime.h>
#include <hip/hip_bf16.h>
#include <stdint.h>

typedef __bf16   bf16x8 __attribute__((ext_vector_type(8)));
typedef float    f32x4  __attribute__((ext_vector_type(4)));
typedef float    fl4    __attribute__((ext_vector_type(4)));
typedef uint32_t u32;
typedef unsigned long long u64;
typedef uint32_t u32x4  __attribute__((ext_vector_type(4)));

#define T_    1024
#define G4H   2048

__device__ __forceinline__ float bf2f(uint16_t b){
  u32 u = ((u32)b) << 16; float f; __builtin_memcpy(&f, &u, 4); return f;
}
__device__ __forceinline__ uint16_t f2bf(float f){
  u32 u; __builtin_memcpy(&u, &f, 4);
  u = u + 0x7fffu + ((u >> 16) & 1u);           // round-nearest-even
  return (uint16_t)(u >> 16);
}
__device__ __forceinline__ float fsig(float x){ return 1.f / (1.f + __expf(-x)); }
__device__ __forceinline__ float ftanh(float x){
  float xc = fminf(fmaxf(x, -15.f), 15.f);
  float e  = __expf(2.f * xc);
  return (e - 1.f) / (e + 1.f);
}
__device__ __forceinline__ void gl_lds16(const void* g, void* l){
  __builtin_amdgcn_global_load_lds((const __attribute__((address_space(1))) void*)g,
                                   (__attribute__((address_space(3))) void*)l, 16, 0, 0);
}
__device__ __forceinline__ u32 umaxv(u32 a, u32 b){ return a > b ? a : b; }

// ---------------- int64-vs-int32 token layout detector ----------------
__global__ void detect_i64(const u32* __restrict__ x, u32* __restrict__ flag){
  int gid = blockIdx.x * 256 + threadIdx.x;     // 0..32767
  u32 v = x[1 + 2 * gid];
  if (v != 0u) atomicOr(flag, 1u);              // 1 -> int32 layout
}

// ---------------- embedding gather + cast to bf16 ----------------
__global__ __launch_bounds__(256) void gather_embed(
    const u32* __restrict__ x, const float* __restrict__ emb,
    uint16_t* __restrict__ e, const u32* __restrict__ flag){
  int row = blockIdx.x * 8 + (threadIdx.x >> 5);      // 0..65535
  int c0  = (threadIdx.x & 31) * 16;
  u32 tok = (*flag != 0u) ? x[row] : x[2 * row];
  const float* s = emb + (size_t)tok * 512 + c0;
  fl4 a = *(const fl4*)(s);
  fl4 b = *(const fl4*)(s + 4);
  fl4 c = *(const fl4*)(s + 8);
  fl4 d = *(const fl4*)(s + 12);
  u32x4 q0 = { (u32)f2bf(a.x) | ((u32)f2bf(a.y) << 16),
               (u32)f2bf(a.z) | ((u32)f2bf(a.w) << 16),
               (u32)f2bf(b.x) | ((u32)f2bf(b.y) << 16),
               (u32)f2bf(b.z) | ((u32)f2bf(b.w) << 16) };
  u32x4 q1 = { (u32)f2bf(c.x) | ((u32)f2bf(c.y) << 16),
               (u32)f2bf(c.z) | ((u32)f2bf(c.w) << 16),
               (u32)f2bf(d.x) | ((u32)f2bf(d.y) << 16),
               (u32)f2bf(d.z) | ((u32)f2bf(d.w) << 16) };
  *(u32x4*)(e + (size_t)row * 512 + c0)     = q0;
  *(u32x4*)(e + (size_t)row * 512 + c0 + 8) = q1;
}

// ---------------- weight prep: w_ih->bf16, w_hh->hi/lo bf16, bias sum ----------------
__global__ __launch_bounds__(256) void prep_w(
    const float* __restrict__ w_ih, const float* __restrict__ w_hh,
    const float* __restrict__ b_ih, const float* __restrict__ b_hh,
    uint16_t* __restrict__ wih, uint16_t* __restrict__ whi,
    uint16_t* __restrict__ wlo, float* __restrict__ bias){
  int bidx = blockIdx.x, t = threadIdx.x;
  if (bidx < 512){
    size_t i0 = (size_t)bidx * 2048 + t * 8;
    fl4 a = *(const fl4*)(w_ih + i0), b = *(const fl4*)(w_ih + i0 + 4);
    u32x4 q = { (u32)f2bf(a.x) | ((u32)f2bf(a.y) << 16),
                (u32)f2bf(a.z) | ((u32)f2bf(a.w) << 16),
                (u32)f2bf(b.x) | ((u32)f2bf(b.y) << 16),
                (u32)f2bf(b.z) | ((u32)f2bf(b.w) << 16) };
    *(u32x4*)(wih + i0) = q;
  } else if (bidx < 1024){
    size_t i0 = (size_t)(bidx - 512) * 2048 + t * 8;
    fl4 a = *(const fl4*)(w_hh + i0), b = *(const fl4*)(w_hh + i0 + 4);
    float v[8] = {a.x,a.y,a.z,a.w,b.x,b.y,b.z,b.w};
    uint16_t hi[8], lo[8];
    #pragma unroll
    for (int j = 0; j < 8; ++j){
      hi[j] = f2bf(v[j]);
      lo[j] = f2bf(v[j] - bf2f(hi[j]));
    }
    u32x4 qh = { (u32)hi[0]|((u32)hi[1]<<16), (u32)hi[2]|((u32)hi[3]<<16),
                 (u32)hi[4]|((u32)hi[5]<<16), (u32)hi[6]|((u32)hi[7]<<16) };
    u32x4 ql = { (u32)lo[0]|((u32)lo[1]<<16), (u32)lo[2]|((u32)lo[3]<<16),
                 (u32)lo[4]|((u32)lo[5]<<16), (u32)lo[6]|((u32)lo[7]<<16) };
    *(u32x4*)(whi + i0) = qh;
    *(u32x4*)(wlo + i0) = ql;
  } else {
    int i0 = t * 8;
    #pragma unroll
    for (int j = 0; j < 8; ++j) bias[i0 + j] = b_ih[i0 + j] + b_hh[i0 + j];
  }
}

// ---------------- x_proj GEMM: [65536x512]bf16 @ [2048x512]^T bf16 -> bf16 ----------------
__global__ __launch_bounds__(256,1) void gemm_xproj(
    const uint16_t* __restrict__ A, const uint16_t* __restrict__ Bw,
    uint16_t* __restrict__ C){
  __shared__ uint16_t As[128 * 64];
  __shared__ uint16_t Bs[128 * 64];
  int m0 = blockIdx.x * 128, n0 = blockIdx.y * 128;
  int tid = threadIdx.x, wid = tid >> 6, l = tid & 63;
  int wm = (wid >> 1) * 64, wn = (wid & 1) * 64;
  f32x4 zz = {0.f, 0.f, 0.f, 0.f};
  f32x4 acc[4][4];
  #pragma unroll
  for (int i = 0; i < 4; ++i)
    #pragma unroll
    for (int j = 0; j < 4; ++j) acc[i][j] = zz;
  const uint16_t* Ap = A  + (size_t)m0 * 512;
  const uint16_t* Bp = Bw + (size_t)n0 * 512;
  for (int kt = 0; kt < 8; ++kt){
    __syncthreads();
    #pragma unroll
    for (int i = 0; i < 4; ++i){
      int c = (i * 4 + wid) * 64 + l;       // 0..1023 chunk (16B) index
      int row = c >> 3, col = c & 7;
      int scol = col ^ (row & 7);           // XOR-swizzle via pre-swizzled source
      gl_lds16(Ap + (size_t)row * 512 + kt * 64 + scol * 8, &As[c * 8]);
      gl_lds16(Bp + (size_t)row * 512 + kt * 64 + scol * 8, &Bs[c * 8]);
    }
    __syncthreads();
    #pragma unroll
    for (int kk = 0; kk < 2; ++kk){
      bf16x8 af[4], bfr[4];
      #pragma unroll
      for (int i = 0; i < 4; ++i){
        int ra = wm + i * 16 + (l & 15);
        int rb = wn + i * 16 + (l & 15);
        int ci = kk * 4 + (l >> 4);
        af[i]  = *(const bf16x8*)((const char*)As + (size_t)ra * 128 + ((ci ^ (ra & 7)) << 4));
        bfr[i] = *(const bf16x8*)((const char*)Bs + (size_t)rb * 128 + ((ci ^ (rb & 7)) << 4));
      }
      #pragma unroll
      for (int mi = 0; mi < 4; ++mi)
        #pragma unroll
        for (int ni = 0; ni < 4; ++ni)
          acc[mi][ni] = __builtin_amdgcn_mfma_f32_16x16x32_bf16(af[mi], bfr[ni], acc[mi][ni], 0, 0, 0);
    }
  }
  #pragma unroll
  for (int mi = 0; mi < 4; ++mi)
    #pragma unroll
    for (int ni = 0; ni < 4; ++ni)
      #pragma unroll
      for (int r = 0; r < 4; ++r){
        int m = m0 + wm + mi * 16 + (l >> 4) * 4 + r;
        int n = n0 + wn + ni * 16 + (l & 15);
        C[(size_t)m * 2048 + n] = f2bf(acc[mi][ni][r]);
      }
}

// ---------------- persistent LSTM recurrence ----------------
// Fence-free design: h stored as packed(hi|lo bf16) + epoch ((t>>1)&1)<<30;
// payload self-validates (valid top-16 ranges & 0xBF memset pairwise disjoint).
// NEW in R6 (transaction-rate focus):
//  * dense flags[128]/group (flag = t+1 per producer wave, after vmcnt(0));
//    ONLY wave 0 polls -> 2 coalesced dword loads per round; waves 1-3 at barrier.
//    Flags are hints; epoch validation remains the correctness gate.
//  * payload: thread owns 4x32B chunks c=j*256+tid (lane-32B-stride, coalesced),
//    8 dwordx4 in ONE asm block + single vmcnt(0) -> 1 RTT, rare retry.
//  * LDS stage: b=4j+wid, slot=l^sigma(b), ds_write_b128, conflict-free.
//  * 3-way split accumulator (breaks 48-long dependent MFMA chain).
//  * all-lane single-dword h store (r=l&3).
// Double-buffer overwrite safety (no fences): producing h(t) requires having read
// all of h(t-1), transitively all WGs finished reading h(t-2).
__global__ __launch_bounds__(256,1) void lstm_rec(
    const uint16_t* __restrict__ xp, const uint16_t* __restrict__ whi,
    const uint16_t* __restrict__ wlo, const float* __restrict__ bias,
    u32* __restrict__ hbuf, u32* __restrict__ flags){
  int bid = blockIdx.x;
  int g = bid & 3;                  // group
  int slice = bid >> 2;             // 0..31
  int tid = threadIdx.x, wid = tid >> 6, l = tid & 63;
  int n_local = wid * 16 + (l & 15);
  int u = slice * 16 + (n_local >> 2);
  int gate = n_local & 3;           // 0:i 1:f 2:g 3:o
  int grow = gate * 512 + u;        // gate row in [0,2048)
  int bquad = (l >> 4) * 4;         // batch base for D rows

  bf16x8 Bhi[16], Blo[16];
  {
    const uint16_t* ph = whi + (size_t)grow * 512 + (l >> 4) * 8;
    const uint16_t* pl = wlo + (size_t)grow * 512 + (l >> 4) * 8;
    #pragma unroll
    for (int ks = 0; ks < 16; ++ks){
      Bhi[ks] = *(const bf16x8*)(ph + ks * 32);
      Blo[ks] = *(const bf16x8*)(pl + ks * 32);
    }
  }
  float biasr = bias[grow];
  float c_[4] = {0.f, 0.f, 0.f, 0.f};
  __shared__ uint16_t hhi[16 * 512];
  __shared__ uint16_t hlo[16 * 512];
  u32* hb0 = hbuf + (size_t)(g * 2 + 0) * (16 * 512);
  u32* hb1 = hbuf + (size_t)(g * 2 + 1) * (16 * 512);
  u32* flagg = flags + g * 128;
  const uint16_t* xpb = xp + (size_t)(g * 16 + bquad) * T_ * G4H + grow;
  int alive = 1000000;              // dead-man budget (whole kernel)
  // payload chunk geometry: chunk c = j*256 + tid (32B each);
  // batch b = c>>6 = 4j + wid; units u0 = (c&63)*8 = l*8.
  int pb_base = wid;                // b = 4j + wid
  // staging slot sigma per batch row
  int brow = l & 15;
  int rsig = (brow & 7) ^ ((brow >> 3) << 2);

  for (int t = 0; t < T_; ++t){
    uint16_t xpr[4];                // issued early -> overlaps the wait
    #pragma unroll
    for (int r = 0; r < 4; ++r)
      xpr[r] = xpb[(size_t)r * T_ * G4H + (size_t)t * G4H];
    if (t > 0){
      // ---- (1) flag spin: wave 0 only, 2 coalesced dword loads per round ----
      if (wid == 0){
        u64 fa = (u64)(uintptr_t)(flagg + l);
        for (;;){
          u32 f0, f1;
          asm volatile(
            "global_load_dword %0, %2, off sc0 sc1\n\t"
            "global_load_dword %1, %2, off offset:256 sc0 sc1\n\t"
            "s_waitcnt vmcnt(0)"
            : "=&v"(f0), "=&v"(f1) : "v"(fa) : "memory");
          if (__all(((int)(f0 - (u32)t) >= 0) && ((int)(f1 - (u32)t) >= 0))) break;
          if (--alive < 0) break;
        }
      }
    }
    __syncthreads();                // A: releases WG when flags say ready;
                                    //    also guards LDS overwrite vs prior reads
    if (t > 0){
      // ---- (2) one-shot coalesced payload: 4x32B chunks, 1 RTT ----
      const char* hb = (const char*)((t & 1) ? hb0 : hb1);
      u64 a0 = (u64)(uintptr_t)(hb + tid * 32);
      u64 a1 = a0 + 8192, a2 = a0 + 16384, a3 = a0 + 24576;
      u32 eoffc = (u32)(((t - 1) >> 1) & 1) << 30;
      u32x4 q0, q1, q2, q3, q4, q5, q6, q7;
      for (;;){
        asm volatile(
          "global_load_dwordx4 %0, %8, off sc0 sc1\n\t"
          "global_load_dwordx4 %1, %8, off offset:16 sc0 sc1\n\t"
          "global_load_dwordx4 %2, %9, off sc0 sc1\n\t"
          "global_load_dwordx4 %3, %9, off offset:16 sc0 sc1\n\t"
          "global_load_dwordx4 %4, %10, off sc0 sc1\n\t"
          "global_load_dwordx4 %5, %10, off offset:16 sc0 sc1\n\t"
          "global_load_dwordx4 %6, %11, off sc0 sc1\n\t"
          "global_load_dwordx4 %7, %11, off offset:16 sc0 sc1\n\t"
          "s_waitcnt vmcnt(0)"
          : "=&v"(q0), "=&v"(q1), "=&v"(q2), "=&v"(q3),
            "=&v"(q4), "=&v"(q5), "=&v"(q6), "=&v"(q7)
          : "v"(a0), "v"(a1), "v"(a2), "v"(a3) : "memory");
        u32 m = 0;
        #define VQ(Q) \
          m = umaxv(m, umaxv((Q.x - eoffc) & 0x7fffffffu, (Q.y - eoffc) & 0x7fffffffu)); \
          m = umaxv(m, umaxv((Q.z - eoffc) & 0x7fffffffu, (Q.w - eoffc) & 0x7fffffffu));
        VQ(q0) VQ(q1) VQ(q2) VQ(q3) VQ(q4) VQ(q5) VQ(q6) VQ(q7)
        #undef VQ
        if (m < 0x3f810000u) break;
        if (--alive < 0) break;
        __builtin_amdgcn_s_sleep(1);
      }
      // ---- (3) unpack hi/lo, sigma-swizzled ds_write_b128 per chunk ----
      u32 V[32];
      *(u32x4*)&V[0]  = q0; *(u32x4*)&V[4]  = q1;
      *(u32x4*)&V[8]  = q2; *(u32x4*)&V[12] = q3;
      *(u32x4*)&V[16] = q4; *(u32x4*)&V[20] = q5;
      *(u32x4*)&V[24] = q6; *(u32x4*)&V[28] = q7;
      #pragma unroll
      for (int j = 0; j < 4; ++j){
        int b = 4 * j + pb_base;
        int ssig = (b & 7) ^ ((b >> 3) << 2);
        int slot = l ^ ssig;
        u32 H[4], L[4];
        #pragma unroll
        for (int i = 0; i < 4; ++i){
          u32 a = V[8*j + 2*i]     - eoffc;
          u32 bb = V[8*j + 2*i + 1] - eoffc;
          H[i] = (a >> 16)     | (bb & 0xffff0000u);
          L[i] = (a & 0xffffu) | (bb << 16);
        }
        u32x4 qh = {H[0], H[1], H[2], H[3]};
        u32x4 ql = {L[0], L[1], L[2], L[3]};
        *(u32x4*)((char*)hhi + b * 1024 + slot * 16) = qh;
        *(u32x4*)((char*)hlo + b * 1024 + slot * 16) = ql;
      }
    }
    __syncthreads();                // B: stage complete before MFMA reads
    f32x4 acc = {0.f, 0.f, 0.f, 0.f};
    if (t > 0){
      f32x4 accA = {0.f,0.f,0.f,0.f}, accB = accA, accC = accA;
      #pragma unroll
      for (int ks = 0; ks < 16; ++ks){
        int slot = (ks * 4 + (l >> 4)) ^ rsig;
        bf16x8 ah = *(const bf16x8*)((const char*)hhi + brow * 1024 + slot * 16);
        bf16x8 al = *(const bf16x8*)((const char*)hlo + brow * 1024 + slot * 16);
        accA = __builtin_amdgcn_mfma_f32_16x16x32_bf16(ah, Bhi[ks], accA, 0, 0, 0);
        accB = __builtin_amdgcn_mfma_f32_16x16x32_bf16(al, Bhi[ks], accB, 0, 0, 0);
        accC = __builtin_amdgcn_mfma_f32_16x16x32_bf16(ah, Blo[ks], accC, 0, 0, 0);
      }
      #pragma unroll
      for (int i = 0; i < 4; ++i) acc[i] = (accA[i] + accB[i]) + accC[i];
    }
    // activations + state update (each 4-lane quad holds i,f,g,o of one unit)
    float hn[4];
    int qb = l & ~3;
    #pragma unroll
    for (int r = 0; r < 4; ++r){
      float pre = acc[r] + bf2f(xpr[r]) + biasr;
      float gi = __shfl(pre, qb + 0, 64);
      float gf = __shfl(pre, qb + 1, 64);
      float gg = __shfl(pre, qb + 2, 64);
      float go = __shfl(pre, qb + 3, 64);
      float i_ = fsig(gi), f_ = fsig(gf), g_ = ftanh(gg), o_ = fsig(go);
      c_[r] = f_ * c_[r] + i_ * g_;
      hn[r] = o_ * ftanh(c_[r]);
    }
    {
      // all-lane store: lane stores batch bquad+(l&3) of its unit u
      int r = l & 3;
      u32 eoffp = (u32)((t >> 1) & 1) << 30;
      uint16_t hi = f2bf(hn[r]);
      uint16_t lo = f2bf(hn[r] - bf2f(hi));
      u32 packed = (((u32)hi << 16) | (u32)lo) + eoffp;
      u32* dst = ((t & 1) ? hb1 : hb0) + (size_t)(bquad + r) * 512 + u;
      __hip_atomic_store(dst, packed, __ATOMIC_RELAXED, __HIP_MEMORY_SCOPE_AGENT);
    }
    asm volatile("s_waitcnt vmcnt(0)" ::: "memory");   // h at IF$ before flag
    if (l == 0)
      __hip_atomic_store(flagg + slice * 4 + wid, (u32)(t + 1),
                         __ATOMIC_RELAXED, __HIP_MEMORY_SCOPE_AGENT);
  }
}

// ---------------- final head: out[64][2] = h_last @ w_out^T + b_out ----------------
__global__ void final_proj(const u32* __restrict__ hbuf, const float* __restrict__ w_out,
                           const float* __restrict__ b_out, float* __restrict__ out){
  int b = blockIdx.x;               // 0..63
  int g = b >> 4, bl = b & 15;
  const u32* hp = hbuf + (size_t)(g * 2 + 1) * (16 * 512) + bl * 512;  // t=1023 slot 1
  int tid = threadIdx.x;            // 64 threads
  float p0 = 0.f, p1 = 0.f;
  #pragma unroll
  for (int j = 0; j < 8; ++j){
    int k = tid * 8 + j;
    u32 pk = hp[k] - 0x40000000u;   // t=1023 epoch ((1023>>1)&1)=1
    float h = bf2f((uint16_t)(pk >> 16)) + bf2f((uint16_t)(pk & 0xffffu));
    p0 += h * w_out[k];
    p1 += h * w_out[512 + k];
  }
  #pragma unroll
  for (int off = 32; off > 0; off >>= 1){
    p0 += __shfl_down(p0, off, 64);
    p1 += __shfl_down(p1, off, 64);
  }
  if (tid == 0){
    out[b * 2 + 0] = p0 + b_out[0];
    out[b * 2 + 1] = p1 + b_out[1];
  }
}

extern "C" void kernel_launch(void* const* d_in, const int* in_sizes, int n_in,
                              void* d_out, int out_size, void* d_ws, size_t ws_size,
                              hipStream_t stream){
  const u32*   x     = (const u32*)d_in[0];
  const float* emb   = (const float*)d_in[1];
  const float* w_ih  = (const float*)d_in[2];
  const float* w_hh  = (const float*)d_in[3];
  const float* b_ih  = (const float*)d_in[4];
  const float* b_hh  = (const float*)d_in[5];
  const float* w_out = (const float*)d_in[6];
  const float* b_out = (const float*)d_in[7];
  char* ws = (char*)d_ws;

  uint16_t* e     = (uint16_t*)(ws);                             // 64 MiB (dead after gemm)
  uint16_t* xp    = (uint16_t*)(ws + 67108864ull);               // 256 MiB
  uint16_t* wih   = (uint16_t*)(ws + 335544320ull);              // 2 MiB
  uint16_t* whi   = (uint16_t*)(ws + 337641472ull);              // 2 MiB
  uint16_t* wlo   = (uint16_t*)(ws + 339738624ull);              // 2 MiB
  float*    bias  = (float*)   (ws + 341835776ull);              // 8 KiB
  u32*      flagw = (u32*)     (ws + 341843968ull);              // 4 B (i64 detect)
  u32*      hbuf  = (u32*)     (ws + 341901312ull);              // 256 KiB
  u32*      flags = (u32*)     (ws + 342163456ull);              // 2 KiB step flags

  hipMemsetAsync(flagw, 0, 4, stream);
  hipMemsetAsync(flags, 0, 4 * 128 * 4, stream);
  hipMemsetAsync(hbuf, 0xBF, 4ull * 8 * 16 * 512, stream);       // invalid in both epochs
  detect_i64  <<<128, 256, 0, stream>>>(x, flagw);
  gather_embed<<<8192, 256, 0, stream>>>(x, emb, e, flagw);
  prep_w      <<<1025, 256, 0, stream>>>(w_ih, w_hh, b_ih, b_hh, wih, whi, wlo, bias);
  gemm_xproj  <<<dim3(512, 16), 256, 0, stream>>>(e, wih, xp);
  lstm_rec    <<<128, 256, 0, stream>>>(xp, whi, wlo, bias, hbuf, flags);
  final_proj  <<<64, 64, 0, stream>>>(hbuf, w_out, b_out, (float*)d_out);
}